// Round 8
// baseline (295.696 us; speedup 1.0000x reference)
//
#include <hip/hip_runtime.h>

typedef __bf16 bhalf;
typedef __bf16 bhalf8 __attribute__((ext_vector_type(8)));
typedef __bf16 bhalf4 __attribute__((ext_vector_type(4)));
typedef float f32x4 __attribute__((ext_vector_type(4)));
typedef float f32x16 __attribute__((ext_vector_type(16)));

typedef __attribute__((address_space(1))) const void* gas_p;
typedef __attribute__((address_space(3))) void* las_p;

#define T_SEQ 2048
#define HIDN  2048
#define NQH   32
#define NKVH  8
#define DH    64
#define NQKV  3072

// ---------------- elementwise cast fp32 -> bf16 ----------------
__global__ __launch_bounds__(256) void cast_bf16_k(const float* __restrict__ in,
                                                   bhalf* __restrict__ out, int n) {
  int i = (blockIdx.x * 256 + threadIdx.x) * 4;
  if (i + 3 < n) {
    float4 v = *(const float4*)(in + i);
    bhalf4 o;
    o[0] = (bhalf)v.x; o[1] = (bhalf)v.y; o[2] = (bhalf)v.z; o[3] = (bhalf)v.w;
    *(bhalf4*)(out + i) = o;
  }
}

// ------------- transpose + cast fp32->bf16, 64x64 tile: out[C][R] = bf16(in[R][C]) ----
__global__ __launch_bounds__(256) void transpose_cast64_k(const float* __restrict__ in,
                                                          bhalf* __restrict__ out,
                                                          int R, int C) {
  __shared__ bhalf tile[64][72];
  int tid = threadIdx.x;
  int bx = blockIdx.x * 64;
  int by = blockIdx.y * 64;
  int rl = tid >> 4, c4 = (tid & 15) * 4;
#pragma unroll
  for (int p = 0; p < 4; ++p) {
    float4 v = *(const float4*)(in + (size_t)(by + rl + 16 * p) * C + bx + c4);
    bhalf4 b;
    b[0] = (bhalf)v.x; b[1] = (bhalf)v.y; b[2] = (bhalf)v.z; b[3] = (bhalf)v.w;
    *(bhalf4*)&tile[rl + 16 * p][c4] = b;
  }
  __syncthreads();
  int c = tid >> 2, r0 = (tid & 3) * 16;
  bhalf8 o0, o1;
#pragma unroll
  for (int j = 0; j < 8; ++j) { o0[j] = tile[r0 + j][c]; o1[j] = tile[r0 + 8 + j][c]; }
  *(bhalf8*)(out + (size_t)(bx + c) * R + by + r0) = o0;
  *(bhalf8*)(out + (size_t)(bx + c) * R + by + r0 + 8) = o1;
}

// ======== GEMM core v2: 64(M) x 128(N) tile, BK=64, mfma_f32_32x32x16_bf16 ========
// 4 waves 2x2; wave tile 32(M) x 64(N) = acc[2] of f32x16. LDS holds tiles in
// FRAGMENT ORDER: chunk = 32 rows x 16 k in exact lane order (lane L -> row L&31,
// k=(L>>5)*8), staged by per-lane-gather global_load_lds (16B/lane). Fragment
// ds_read_b128 is then base + lane*16 -> ZERO bank conflicts. A = 8 chunks (2 mt
// x 4 ks), B = 16 chunks (4 nt x 4 ks); 24 KB LDS -> 6 blocks/CU.
__device__ __forceinline__ void gemm_core32(const bhalf* __restrict__ A,
                                            const bhalf* __restrict__ Bt,
                                            int K, int Klen, int bm, int bn, int tid,
                                            bhalf* As, bhalf* Bs, f32x16 acc[2]) {
  int lane = tid & 63, wv = tid >> 6;
  int r32 = lane & 31, khi = (lane >> 5) * 8;
  // wave wv stages A-chunks {2wv, 2wv+1}, B-chunks {4wv..4wv+3}
  const bhalf* ag[2];
  const bhalf* bg[4];
#pragma unroll
  for (int i = 0; i < 2; ++i) {
    int a = 2 * wv + i;
    ag[i] = A + (size_t)(bm + (a >> 2) * 32 + r32) * K + (a & 3) * 16 + khi;
  }
#pragma unroll
  for (int j = 0; j < 4; ++j) {
    int b = 4 * wv + j;
    bg[j] = Bt + (size_t)(bn + (b >> 2) * 32 + r32) * K + (b & 3) * 16 + khi;
  }
  bhalf* adst = As + (2 * wv) * 512;
  bhalf* bdst = Bs + (4 * wv) * 512;
  int mt = wv >> 1, ntb = (wv & 1) * 2;

  for (int k0 = 0; k0 < Klen; k0 += 64) {
#pragma unroll
    for (int i = 0; i < 2; ++i)
      __builtin_amdgcn_global_load_lds((gas_p)(ag[i] + k0), (las_p)(adst + i * 512), 16, 0, 0);
#pragma unroll
    for (int j = 0; j < 4; ++j)
      __builtin_amdgcn_global_load_lds((gas_p)(bg[j] + k0), (las_p)(bdst + j * 512), 16, 0, 0);
    __syncthreads();
#pragma unroll
    for (int ks = 0; ks < 4; ++ks) {
      bhalf8 af  = *(const bhalf8*)&As[(mt * 4 + ks) * 512 + lane * 8];
      bhalf8 bf0 = *(const bhalf8*)&Bs[(ntb * 4 + ks) * 512 + lane * 8];
      bhalf8 bf1 = *(const bhalf8*)&Bs[((ntb + 1) * 4 + ks) * 512 + lane * 8];
      acc[0] = __builtin_amdgcn_mfma_f32_32x32x16_bf16(af, bf0, acc[0], 0, 0, 0);
      acc[1] = __builtin_amdgcn_mfma_f32_32x32x16_bf16(af, bf1, acc[1], 0, 0, 0);
    }
    __syncthreads();
  }
}

// ---------------- GEMM1 + fused RMSNorm + RoPE + split + cast (+ direct V^T) ---------
// 64x128 tile: N-tile 128 = 2 heads; wave's 64 cols = exactly one head
// hh = 2*blockIdx.x + (wv&1). C/D: col = lane&31 (= d), row = (r&3)+8*(r>>2)+4*(lane>>5).
// RoPE pair (d, d+32) = (acc[0][r], acc[1][r]) — same lane/reg, no shuffles.
__global__ __launch_bounds__(256) void gemm1_fused_k(const bhalf* __restrict__ A,
                                                     const bhalf* __restrict__ Bt,
                                                     const int* __restrict__ pos,
                                                     const float* __restrict__ qw,
                                                     const float* __restrict__ kw,
                                                     bhalf* __restrict__ qo,
                                                     bhalf* __restrict__ ko,
                                                     bhalf* __restrict__ vt) {
  __shared__ __align__(16) bhalf As[8 * 512];
  __shared__ __align__(16) bhalf Bs[16 * 512];
  int tid = threadIdx.x, lane = tid & 63, wv = tid >> 6;
  int r32 = lane & 31;
  int bm = blockIdx.y * 64, bn = blockIdx.x * 128;
  f32x16 acc[2];
#pragma unroll
  for (int r = 0; r < 16; ++r) { acc[0][r] = 0.f; acc[1][r] = 0.f; }

  gemm_core32(A, Bt, HIDN, HIDN, bm, bn, tid, As, Bs, acc);

  int hh = blockIdx.x * 2 + (wv & 1);
  int wm = (wv >> 1) * 32;
  int rhi = 4 * (lane >> 5);
  if (hh < 40) {
    const float* wptr = (hh < 32) ? qw : kw;
    float w0 = wptr[r32], w1 = wptr[r32 + 32];
    float f0 = exp2f((float)r32 * -0.6228615177913804f);  // theta^(-d/32)
#pragma unroll
    for (int r = 0; r < 16; ++r) {
      int row = (r & 3) + 8 * (r >> 2) + rhi;
      int trow = bm + wm + row;
      float x0 = acc[0][r], x1 = acc[1][r];
      float ss = x0 * x0 + x1 * x1;
      ss += __shfl_xor(ss, 1);
      ss += __shfl_xor(ss, 2);
      ss += __shfl_xor(ss, 4);
      ss += __shfl_xor(ss, 8);
      ss += __shfl_xor(ss, 16);
      float sc = rsqrtf(ss * (1.0f / 64.0f) + 1e-5f);
      float y0 = x0 * sc * w0, y1 = x1 * sc * w1;
      float ang = (float)pos[trow] * f0;
      float c = cosf(ang), s = sinf(ang);
      float o0 = y0 * c - y1 * s, o1 = y1 * c + y0 * s;
      if (hh < 32) {
        bhalf* dst = qo + (size_t)trow * 2048 + hh * 64 + r32;
        dst[0] = (bhalf)o0; dst[32] = (bhalf)o1;
      } else {
        bhalf* dst = ko + (size_t)trow * 512 + (hh - 32) * 64 + r32;
        dst[0] = (bhalf)o0; dst[32] = (bhalf)o1;
      }
    }
  } else {
    // V: write transposed directly — vt[(hh-40)*64 + d][trow]
#pragma unroll
    for (int r = 0; r < 16; ++r) {
      int row = (r & 3) + 8 * (r >> 2) + rhi;
      int trow = bm + wm + row;
      vt[(size_t)((hh - 40) * 64 + r32) * 2048 + trow] = (bhalf)acc[0][r];
      vt[(size_t)((hh - 40) * 64 + r32 + 32) * 2048 + trow] = (bhalf)acc[1][r];
    }
  }
}

// ---------------- GEMM2 (64x128 tile, split-K=2): partial fp32 out ----------------
__global__ __launch_bounds__(256) void gemm2_k(const bhalf* __restrict__ A,
                                               const bhalf* __restrict__ Bt,
                                               float* __restrict__ Cpart) {
  __shared__ __align__(16) bhalf As[8 * 512];
  __shared__ __align__(16) bhalf Bs[16 * 512];
  int tid = threadIdx.x, lane = tid & 63, wv = tid >> 6;
  int r32 = lane & 31;
  int bm = blockIdx.y * 64, bn = blockIdx.x * 128;
  int slice = blockIdx.z;
  f32x16 acc[2];
#pragma unroll
  for (int r = 0; r < 16; ++r) { acc[0][r] = 0.f; acc[1][r] = 0.f; }

  gemm_core32(A + slice * 1024, Bt + slice * 1024, HIDN, 1024, bm, bn, tid, As, Bs, acc);

  float* C = Cpart + (size_t)slice * (T_SEQ * HIDN);
  int wm = (wv >> 1) * 32, wn = (wv & 1) * 64;
  int rhi = 4 * (lane >> 5);
#pragma unroll
  for (int r = 0; r < 16; ++r) {
    int row = (r & 3) + 8 * (r >> 2) + rhi;
    size_t base = (size_t)(bm + wm + row) * 2048 + bn + wn + r32;
    C[base] = acc[0][r];
    C[base + 32] = acc[1][r];
  }
}

// ---------------- split-K reduce: out = p0 + p1 ----------------
__global__ __launch_bounds__(256) void add2_k(const float* __restrict__ p0,
                                              const float* __restrict__ p1,
                                              float* __restrict__ out) {
  int i = (blockIdx.x * 256 + threadIdx.x) * 4;
  float4 a = *(const float4*)(p0 + i);
  float4 b = *(const float4*)(p1 + i);
  float4 o = {a.x + b.x, a.y + b.y, a.z + b.z, a.w + b.w};
  *(float4*)(out + i) = o;
}

// ---------------- flash attention (causal GQA), fixed-max softmax ----------------
// (R4 version — verified best.) grid (NQH, 32): block = (head, 64 q-rows),
// qt = 31 - by (heavy first). 4 waves; wave owns 16 q-rows. s-chunk 64, K/V^T
// double-buffered via global_load_lds + XOR swizzle, 1 barrier/chunk. Interior
// chunks take an unmasked fast path; only the diagonal chunk (c==qt) masks.
__global__ __launch_bounds__(256) void attn_k(const bhalf* __restrict__ q,
                                              const bhalf* __restrict__ k,
                                              const bhalf* __restrict__ vt,
                                              bhalf* __restrict__ o) {
  __shared__ __align__(16) bhalf Kb[2][4096];
  __shared__ __align__(16) bhalf Vb[2][4096];
  __shared__ __align__(16) bhalf Pb[4][16][72];
  int tid = threadIdx.x, lane = tid & 63, w = tid >> 6;
  int h = blockIdx.x, kh = h >> 2;
  int qt = 31 - blockIdx.y;
  int qb = qt * 64;
  int m16 = lane & 15, q4 = lane >> 4;
  int wrow0 = qb + w * 16;

  const float C1 = 0.18033688011112042f;  // 0.125 * log2(e)
  const float C2 = 11.541560327111707f;   // 8 * log2(e)

  const bhalf* qp = q + (size_t)(wrow0 + m16) * 2048 + h * 64;
  bhalf8 qf0 = *(const bhalf8*)(qp + q4 * 8);
  bhalf8 qf1 = *(const bhalf8*)(qp + 32 + q4 * 8);

  int srow = tid >> 3;
  int scol = ((tid & 7) ^ (srow & 7)) * 8;
  const bhalf* ksrc = k + (size_t)srow * 512 + kh * 64 + scol;
  const bhalf* vsrc = vt + (size_t)(kh * 64 + srow) * 2048 + scol;
  bhalf* kdst = &Kb[0][0] + w * 512;
  bhalf* vdst = &Vb[0][0] + w * 512;

  auto stage = [&](int c) {
    int buf = c & 1, s0 = c * 64;
#pragma unroll
    for (int j = 0; j < 2; ++j) {
      __builtin_amdgcn_global_load_lds((gas_p)(ksrc + (size_t)(s0 + j * 32) * 512),
                                       (las_p)(kdst + buf * 4096 + j * 2048), 16, 0, 0);
      __builtin_amdgcn_global_load_lds((gas_p)(vsrc + (size_t)(j * 32) * 2048 + s0),
                                       (las_p)(vdst + buf * 4096 + j * 2048), 16, 0, 0);
    }
  };

  f32x4 zero4 = {0.f, 0.f, 0.f, 0.f};
  f32x4 oac[4];
  float psum[4] = {0.f, 0.f, 0.f, 0.f};
#pragma unroll
  for (int ni = 0; ni < 4; ++ni) oac[ni] = zero4;
  int swz = m16 & 7;

  stage(0);
  for (int c = 0; c <= qt; ++c) {
    __syncthreads();
    if (c < qt) stage(c + 1);
    int buf = c & 1, s0 = c * 64;
    if (c < qt) {
      bhalf8 kf[4][2];
#pragma unroll
      for (int st = 0; st < 4; ++st)
#pragma unroll
        for (int ks = 0; ks < 2; ++ks)
          kf[st][ks] = *(const bhalf8*)&Kb[buf][(st * 16 + m16) * 64 + (((ks * 4 + q4) ^ swz) * 8)];
      f32x4 sv[4];
#pragma unroll
      for (int st = 0; st < 4; ++st) {
        f32x4 t0 = __builtin_amdgcn_mfma_f32_16x16x32_bf16(qf0, kf[st][0], zero4, 0, 0, 0);
        sv[st] = __builtin_amdgcn_mfma_f32_16x16x32_bf16(qf1, kf[st][1], t0, 0, 0, 0);
      }
#pragma unroll
      for (int st = 0; st < 4; ++st)
#pragma unroll
        for (int r = 0; r < 4; ++r) {
          float pe = exp2f(sv[st][r] * C1 - C2);
          psum[r] += pe;
          Pb[w][q4 * 4 + r][st * 16 + m16] = (bhalf)pe;
        }
      bhalf8 vf[4][2];
#pragma unroll
      for (int ni = 0; ni < 4; ++ni)
#pragma unroll
        for (int ks = 0; ks < 2; ++ks)
          vf[ni][ks] = *(const bhalf8*)&Vb[buf][(ni * 16 + m16) * 64 + (((ks * 4 + q4) ^ swz) * 8)];
      bhalf8 ap0 = *(const bhalf8*)&Pb[w][m16][q4 * 8];
      bhalf8 ap1 = *(const bhalf8*)&Pb[w][m16][32 + q4 * 8];
#pragma unroll
      for (int ni = 0; ni < 4; ++ni) {
        oac[ni] = __builtin_amdgcn_mfma_f32_16x16x32_bf16(ap0, vf[ni][0], oac[ni], 0, 0, 0);
        oac[ni] = __builtin_amdgcn_mfma_f32_16x16x32_bf16(ap1, vf[ni][1], oac[ni], 0, 0, 0);
      }
    } else {
      bhalf8 kf[4][2];
      f32x4 sv[4];
#pragma unroll
      for (int st = 0; st < 4; ++st)
        if (st <= w) {
#pragma unroll
          for (int ks = 0; ks < 2; ++ks)
            kf[st][ks] = *(const bhalf8*)&Kb[buf][(st * 16 + m16) * 64 + (((ks * 4 + q4) ^ swz) * 8)];
          f32x4 t0 = __builtin_amdgcn_mfma_f32_16x16x32_bf16(qf0, kf[st][0], zero4, 0, 0, 0);
          sv[st] = __builtin_amdgcn_mfma_f32_16x16x32_bf16(qf1, kf[st][1], t0, 0, 0, 0);
        }
      int stwr = (w >= 2) ? 3 : 1;
#pragma unroll
      for (int st = 0; st < 4; ++st) {
        if (st > stwr) continue;
#pragma unroll
        for (int r = 0; r < 4; ++r) {
          float pe = 0.f;
          if (st <= w) {
            int trow = wrow0 + q4 * 4 + r;
            int col = s0 + st * 16 + m16;
            pe = (col <= trow) ? exp2f(sv[st][r] * C1 - C2) : 0.f;
          }
          psum[r] += pe;
          Pb[w][q4 * 4 + r][st * 16 + m16] = (bhalf)pe;
        }
      }
      int ksmax = (w >= 2) ? 1 : 0;
      bhalf8 vf[4][2];
#pragma unroll
      for (int ni = 0; ni < 4; ++ni)
#pragma unroll
        for (int ks = 0; ks < 2; ++ks)
          if (ks <= ksmax)
            vf[ni][ks] = *(const bhalf8*)&Vb[buf][(ni * 16 + m16) * 64 + (((ks * 4 + q4) ^ swz) * 8)];
      bhalf8 ap0 = *(const bhalf8*)&Pb[w][m16][q4 * 8];
#pragma unroll
      for (int ni = 0; ni < 4; ++ni)
        oac[ni] = __builtin_amdgcn_mfma_f32_16x16x32_bf16(ap0, vf[ni][0], oac[ni], 0, 0, 0);
      if (ksmax) {
        bhalf8 ap1 = *(const bhalf8*)&Pb[w][m16][32 + q4 * 8];
#pragma unroll
        for (int ni = 0; ni < 4; ++ni)
          oac[ni] = __builtin_amdgcn_mfma_f32_16x16x32_bf16(ap1, vf[ni][1], oac[ni], 0, 0, 0);
      }
    }
  }
#pragma unroll
  for (int r = 0; r < 4; ++r) {
    float ps = psum[r];
    ps += __shfl_xor(ps, 1);
    ps += __shfl_xor(ps, 2);
    ps += __shfl_xor(ps, 4);
    ps += __shfl_xor(ps, 8);
    psum[r] = 1.0f / ps;
  }
#pragma unroll
  for (int ni = 0; ni < 4; ++ni)
#pragma unroll
    for (int r = 0; r < 4; ++r) {
      int trow = wrow0 + q4 * 4 + r;
      o[(size_t)trow * 2048 + h * 64 + ni * 16 + m16] = (bhalf)(oac[ni][r] * psum[r]);
    }
}

extern "C" void kernel_launch(void* const* d_in, const int* in_sizes, int n_in,
                              void* d_out, int out_size, void* d_ws, size_t ws_size,
                              hipStream_t stream) {
  const int* positions = (const int*)d_in[0];
  const float* hidden  = (const float*)d_in[1];
  const float* w_qkv   = (const float*)d_in[2];
  const float* w_out   = (const float*)d_in[3];
  const float* q_ln    = (const float*)d_in[4];
  const float* k_ln    = (const float*)d_in[5];
  float* out = (float*)d_out;

  char* wsp = (char*)d_ws;
  bhalf* woutT   = (bhalf*)(wsp);                 //  0 .. 8.39 MB
  bhalf* attn_bf = (bhalf*)(wsp + 8388608);       //  8.39 .. 16.78
  float* part0   = (float*)(wsp + 16777216);      // 16.78 .. 33.55 (overlays hid/wqkvT)
  float* part1   = (float*)(wsp + 33554432);      // 33.55 .. 50.33
  bhalf* hid_bf  = (bhalf*)(wsp + 16777216);      // dead after gemm1
  bhalf* wqkvT   = (bhalf*)(wsp + 25165824);      // dead after gemm1
  bhalf* q_bf    = (bhalf*)(wsp + 50331648);      // 50.33 .. 58.72
  bhalf* k_bf    = (bhalf*)(wsp + 58720256);      // 58.72 .. 60.82
  bhalf* vt_g    = (bhalf*)(wsp + 60817408);      // 60.82 .. 62.91

  cast_bf16_k<<<T_SEQ * HIDN / 1024, 256, 0, stream>>>(hidden, hid_bf, T_SEQ * HIDN);
  transpose_cast64_k<<<dim3(NQKV / 64, HIDN / 64), 256, 0, stream>>>(w_qkv, wqkvT, HIDN, NQKV);
  transpose_cast64_k<<<dim3(HIDN / 64, HIDN / 64), 256, 0, stream>>>(w_out, woutT, HIDN, HIDN);
  gemm1_fused_k<<<dim3(NQKV / 128, T_SEQ / 64), 256, 0, stream>>>(
      hid_bf, wqkvT, positions, q_ln, k_ln, q_bf, k_bf, vt_g);
  attn_k<<<dim3(NQH, 32), 256, 0, stream>>>(q_bf, k_bf, vt_g, attn_bf);
  gemm2_k<<<dim3(HIDN / 128, T_SEQ / 64, 2), 256, 0, stream>>>(attn_bf, woutT, part0);
  add2_k<<<T_SEQ * HIDN / 1024, 256, 0, stream>>>(part0, part1, out);
}

// Round 9
// 232.910 us; speedup vs baseline: 1.2696x; 1.2696x over previous
//
#include <hip/hip_runtime.h>

typedef __bf16 bhalf;
typedef __bf16 bhalf8 __attribute__((ext_vector_type(8)));
typedef __bf16 bhalf4 __attribute__((ext_vector_type(4)));
typedef float f32x4 __attribute__((ext_vector_type(4)));

typedef __attribute__((address_space(1))) const void* gas_p;
typedef __attribute__((address_space(3))) void* las_p;

#define T_SEQ 2048
#define HIDN  2048
#define NQH   32
#define NKVH  8
#define DH    64
#define NQKV  3072

// ---------------- elementwise cast fp32 -> bf16 ----------------
__global__ __launch_bounds__(256) void cast_bf16_k(const float* __restrict__ in,
                                                   bhalf* __restrict__ out, int n) {
  int i = (blockIdx.x * 256 + threadIdx.x) * 4;
  if (i + 3 < n) {
    float4 v = *(const float4*)(in + i);
    bhalf4 o;
    o[0] = (bhalf)v.x; o[1] = (bhalf)v.y; o[2] = (bhalf)v.z; o[3] = (bhalf)v.w;
    *(bhalf4*)(out + i) = o;
  }
}

// ------------- transpose + cast fp32->bf16, 64x64 tile: out[C][R] = bf16(in[R][C]) ----
__global__ __launch_bounds__(256) void transpose_cast64_k(const float* __restrict__ in,
                                                          bhalf* __restrict__ out,
                                                          int R, int C) {
  __shared__ bhalf tile[64][72];
  int tid = threadIdx.x;
  int bx = blockIdx.x * 64;
  int by = blockIdx.y * 64;
  int rl = tid >> 4, c4 = (tid & 15) * 4;
#pragma unroll
  for (int p = 0; p < 4; ++p) {
    float4 v = *(const float4*)(in + (size_t)(by + rl + 16 * p) * C + bx + c4);
    bhalf4 b;
    b[0] = (bhalf)v.x; b[1] = (bhalf)v.y; b[2] = (bhalf)v.z; b[3] = (bhalf)v.w;
    *(bhalf4*)&tile[rl + 16 * p][c4] = b;
  }
  __syncthreads();
  int c = tid >> 2, r0 = (tid & 3) * 16;
  bhalf8 o0, o1;
#pragma unroll
  for (int j = 0; j < 8; ++j) { o0[j] = tile[r0 + j][c]; o1[j] = tile[r0 + 8 + j][c]; }
  *(bhalf8*)(out + (size_t)(bx + c) * R + by + r0) = o0;
  *(bhalf8*)(out + (size_t)(bx + c) * R + by + r0 + 8) = o1;
}

// ---------------- bf16 transpose: out[C][R] = in[R][C] ----------------
__global__ __launch_bounds__(256) void transpose_bf16_k(const bhalf* __restrict__ in,
                                                        bhalf* __restrict__ out, int R, int C) {
  __shared__ bhalf tile[32][33];
  int bx = blockIdx.x * 32;
  int by = blockIdx.y * 32;
  int tx = threadIdx.x & 31, ty = threadIdx.x >> 5;
#pragma unroll
  for (int p = 0; p < 4; ++p)
    tile[ty + 8 * p][tx] = in[(size_t)(by + ty + 8 * p) * C + bx + tx];
  __syncthreads();
#pragma unroll
  for (int p = 0; p < 4; ++p)
    out[(size_t)(bx + ty + 8 * p) * R + by + tx] = tile[tx][ty + 8 * p];
}

// -------- GEMM core A (R4-proven): 128(M) x 64(N) tile, BK=64, single-buf ----------
// 4 waves stacked in M (wave tile 32x64, 2 m-frags). XOR-swizzled LDS staged via
// coalesced global_load_lds width=16. 2 barriers/iter. LDS 24 KB.
__device__ __forceinline__ void gemm_core(const bhalf* __restrict__ A,
                                          const bhalf* __restrict__ Bt,
                                          int Kstride, int Klen,
                                          int bm, int bn, int tid,
                                          bhalf* As, bhalf* Bs, f32x4 acc[2][4]) {
  int lane = tid & 63, wv = tid >> 6;
  int m16 = lane & 15, q4 = lane >> 4;
  int srow = tid >> 3;                       // 0..31
  int scol = ((tid & 7) ^ (srow & 7)) * 8;   // XOR-swizzled source col block
  const bhalf* asrc = A + (size_t)(bm + srow) * Kstride + scol;
  const bhalf* bsrc = Bt + (size_t)(bn + srow) * Kstride + scol;
  bhalf* adst = As + (wv * 8) * 64;
  bhalf* bdst = Bs + (wv * 8) * 64;
  int swz = m16 & 7;

  for (int k0 = 0; k0 < Klen; k0 += 64) {
#pragma unroll
    for (int c = 0; c < 4; ++c)
      __builtin_amdgcn_global_load_lds((gas_p)(asrc + (size_t)(c * 32) * Kstride + k0),
                                       (las_p)(adst + c * 2048), 16, 0, 0);
#pragma unroll
    for (int c = 0; c < 2; ++c)
      __builtin_amdgcn_global_load_lds((gas_p)(bsrc + (size_t)(c * 32) * Kstride + k0),
                                       (las_p)(bdst + c * 2048), 16, 0, 0);
    __syncthreads();
    bhalf8 af[2][2], bf[4][2];
#pragma unroll
    for (int mi = 0; mi < 2; ++mi)
#pragma unroll
      for (int ks = 0; ks < 2; ++ks)
        af[mi][ks] = *(const bhalf8*)&As[(wv * 32 + mi * 16 + m16) * 64 +
                                         (((ks * 4 + q4) ^ swz) * 8)];
#pragma unroll
    for (int ni = 0; ni < 4; ++ni)
#pragma unroll
      for (int ks = 0; ks < 2; ++ks)
        bf[ni][ks] = *(const bhalf8*)&Bs[(ni * 16 + m16) * 64 +
                                         (((ks * 4 + q4) ^ swz) * 8)];
#pragma unroll
    for (int mi = 0; mi < 2; ++mi)
#pragma unroll
      for (int ni = 0; ni < 4; ++ni) {
        acc[mi][ni] = __builtin_amdgcn_mfma_f32_16x16x32_bf16(af[mi][0], bf[ni][0], acc[mi][ni], 0, 0, 0);
        acc[mi][ni] = __builtin_amdgcn_mfma_f32_16x16x32_bf16(af[mi][1], bf[ni][1], acc[mi][ni], 0, 0, 0);
      }
    __syncthreads();
  }
}

// -------- GEMM core B: 128(M) x 64(N) tile, BK=128, single-buf, 2 barriers/iter ------
// Same wave layout as core A but 128-wide K-tile: halves barrier count (32 vs 64
// for K=2048). LDS 48 KB -> 3 blocks/CU, which equals gemm1's grid cap (768/256),
// so the LDS growth is free. Coalesced staging: per call 256 threads cover 16 rows
// x 128 cols (thread t: row t>>4, phys col-block t&15 holding logical (t&15)^(row&7)).
__device__ __forceinline__ void gemm_core_bk128(const bhalf* __restrict__ A,
                                                const bhalf* __restrict__ Bt,
                                                int K, int bm, int bn, int tid,
                                                bhalf* As, bhalf* Bs, f32x4 acc[2][4]) {
  int lane = tid & 63, wv = tid >> 6;
  int m16 = lane & 15, q4 = lane >> 4;
  int srow = tid >> 4;                        // 0..15
  int scol = ((tid & 15) ^ (srow & 7)) * 8;   // XOR-swizzled source col block
  const bhalf* asrc = A + (size_t)(bm + srow) * K + scol;
  const bhalf* bsrc = Bt + (size_t)(bn + srow) * K + scol;
  bhalf* adst = As + (4 * wv) * 128;          // wave covers rows 4wv..4wv+3 per call
  bhalf* bdst = Bs + (4 * wv) * 128;
  int swz = m16 & 7;

  for (int k0 = 0; k0 < K; k0 += 128) {
#pragma unroll
    for (int c = 0; c < 8; ++c)
      __builtin_amdgcn_global_load_lds((gas_p)(asrc + (size_t)(c * 16) * K + k0),
                                       (las_p)(adst + c * 16 * 128), 16, 0, 0);
#pragma unroll
    for (int c = 0; c < 4; ++c)
      __builtin_amdgcn_global_load_lds((gas_p)(bsrc + (size_t)(c * 16) * K + k0),
                                       (las_p)(bdst + c * 16 * 128), 16, 0, 0);
    __syncthreads();
#pragma unroll
    for (int ks = 0; ks < 4; ++ks) {
      bhalf8 af[2], bf[4];
#pragma unroll
      for (int mi = 0; mi < 2; ++mi)
        af[mi] = *(const bhalf8*)&As[(wv * 32 + mi * 16 + m16) * 128 +
                                     (((ks * 4 + q4) ^ swz) * 8)];
#pragma unroll
      for (int ni = 0; ni < 4; ++ni)
        bf[ni] = *(const bhalf8*)&Bs[(ni * 16 + m16) * 128 +
                                     (((ks * 4 + q4) ^ swz) * 8)];
#pragma unroll
      for (int mi = 0; mi < 2; ++mi)
#pragma unroll
        for (int ni = 0; ni < 4; ++ni)
          acc[mi][ni] = __builtin_amdgcn_mfma_f32_16x16x32_bf16(af[mi], bf[ni], acc[mi][ni], 0, 0, 0);
    }
    __syncthreads();
  }
}

// ---------------- GEMM1 + fused RMSNorm + RoPE + split + cast ----------------
// 128x64 tile, BK=128 core; N-tile 64 == one head (h: 0..31 q, 32..39 k, 40..47 v).
__global__ __launch_bounds__(256) void gemm1_fused_k(const bhalf* __restrict__ A,
                                                     const bhalf* __restrict__ Bt,
                                                     const int* __restrict__ pos,
                                                     const float* __restrict__ qw,
                                                     const float* __restrict__ kw,
                                                     bhalf* __restrict__ qo,
                                                     bhalf* __restrict__ ko,
                                                     bhalf* __restrict__ vo) {
  __shared__ __align__(16) bhalf As[128 * 128];
  __shared__ __align__(16) bhalf Bs[64 * 128];
  int tid = threadIdx.x, lane = tid & 63, wv = tid >> 6;
  int m16 = lane & 15, q4 = lane >> 4;
  int bm = blockIdx.y * 128, bn = blockIdx.x * 64, h = blockIdx.x;
  f32x4 zero4 = {0.f, 0.f, 0.f, 0.f};
  f32x4 acc[2][4];
#pragma unroll
  for (int mi = 0; mi < 2; ++mi)
#pragma unroll
    for (int ni = 0; ni < 4; ++ni) acc[mi][ni] = zero4;

  gemm_core_bk128(A, Bt, HIDN, bm, bn, tid, As, Bs, acc);

  if (h < 40) {
    float wd[4];
    const float* wptr = (h < 32) ? qw : kw;
#pragma unroll
    for (int ni = 0; ni < 4; ++ni) wd[ni] = wptr[ni * 16 + m16];
    float f0 = exp2f((float)m16 * -0.6228615177913804f);
    float f1 = f0 * 0.001f;  // theta^(-16/32) = 1e-3
#pragma unroll
    for (int mi = 0; mi < 2; ++mi)
#pragma unroll
      for (int r = 0; r < 4; ++r) {
        int trow = bm + wv * 32 + mi * 16 + q4 * 4 + r;
        float x0 = acc[mi][0][r], x1 = acc[mi][1][r], x2 = acc[mi][2][r], x3 = acc[mi][3][r];
        float ss = x0 * x0 + x1 * x1 + x2 * x2 + x3 * x3;
        ss += __shfl_xor(ss, 1);
        ss += __shfl_xor(ss, 2);
        ss += __shfl_xor(ss, 4);
        ss += __shfl_xor(ss, 8);
        float sc = rsqrtf(ss * (1.0f / 64.0f) + 1e-5f);
        float y0 = x0 * sc * wd[0], y1 = x1 * sc * wd[1];
        float y2 = x2 * sc * wd[2], y3 = x3 * sc * wd[3];
        float p = (float)pos[trow];
        float a0 = p * f0, a1 = p * f1;
        float c0 = cosf(a0), s0 = sinf(a0), c1 = cosf(a1), s1 = sinf(a1);
        float o0 = y0 * c0 - y2 * s0, o2 = y2 * c0 + y0 * s0;
        float o1 = y1 * c1 - y3 * s1, o3 = y3 * c1 + y1 * s1;
        bhalf* dst = (h < 32) ? (qo + (size_t)trow * 2048 + h * 64 + m16)
                              : (ko + (size_t)trow * 512 + (h - 32) * 64 + m16);
        dst[0] = (bhalf)o0; dst[16] = (bhalf)o1; dst[32] = (bhalf)o2; dst[48] = (bhalf)o3;
      }
  } else {
#pragma unroll
    for (int mi = 0; mi < 2; ++mi)
#pragma unroll
      for (int r = 0; r < 4; ++r) {
        int trow = bm + wv * 32 + mi * 16 + q4 * 4 + r;
        bhalf* dst = vo + (size_t)trow * 512 + (h - 40) * 64 + m16;
        dst[0] = (bhalf)acc[mi][0][r]; dst[16] = (bhalf)acc[mi][1][r];
        dst[32] = (bhalf)acc[mi][2][r]; dst[48] = (bhalf)acc[mi][3][r];
      }
  }
}

// ---------------- GEMM2 (128x64 tile, BK=64 core, split-K=2): partial fp32 out -------
__global__ __launch_bounds__(256) void gemm2_k(const bhalf* __restrict__ A,
                                               const bhalf* __restrict__ Bt,
                                               float* __restrict__ Cpart) {
  __shared__ __align__(16) bhalf As[128 * 64];
  __shared__ __align__(16) bhalf Bs[64 * 64];
  int tid = threadIdx.x, lane = tid & 63, wv = tid >> 6;
  int m16 = lane & 15, q4 = lane >> 4;
  int bm = blockIdx.y * 128, bn = blockIdx.x * 64;
  int slice = blockIdx.z;
  f32x4 zero4 = {0.f, 0.f, 0.f, 0.f};
  f32x4 acc[2][4];
#pragma unroll
  for (int mi = 0; mi < 2; ++mi)
#pragma unroll
    for (int ni = 0; ni < 4; ++ni) acc[mi][ni] = zero4;

  gemm_core(A + slice * 1024, Bt + slice * 1024, HIDN, 1024, bm, bn, tid, As, Bs, acc);

  float* C = Cpart + (size_t)slice * (T_SEQ * HIDN);
#pragma unroll
  for (int mi = 0; mi < 2; ++mi)
#pragma unroll
    for (int r = 0; r < 4; ++r) {
      size_t base = (size_t)(bm + wv * 32 + mi * 16 + q4 * 4 + r) * 2048 + bn + m16;
      C[base] = acc[mi][0][r]; C[base + 16] = acc[mi][1][r];
      C[base + 32] = acc[mi][2][r]; C[base + 48] = acc[mi][3][r];
    }
}

// ---------------- split-K reduce: out = p0 + p1 ----------------
__global__ __launch_bounds__(256) void add2_k(const float* __restrict__ p0,
                                              const float* __restrict__ p1,
                                              float* __restrict__ out) {
  int i = (blockIdx.x * 256 + threadIdx.x) * 4;
  float4 a = *(const float4*)(p0 + i);
  float4 b = *(const float4*)(p1 + i);
  float4 o = {a.x + b.x, a.y + b.y, a.z + b.z, a.w + b.w};
  *(float4*)(out + i) = o;
}

// ---------------- flash attention (causal GQA), fixed-max softmax ----------------
// (R4 version — verified best.) grid (NQH, 32): block = (head, 64 q-rows),
// qt = 31 - by (heavy first). 4 waves; wave owns 16 q-rows. s-chunk 64, K/V^T
// double-buffered via global_load_lds + XOR swizzle, 1 barrier/chunk. Interior
// chunks take an unmasked fast path; only the diagonal chunk (c==qt) masks.
__global__ __launch_bounds__(256) void attn_k(const bhalf* __restrict__ q,
                                              const bhalf* __restrict__ k,
                                              const bhalf* __restrict__ vt,
                                              bhalf* __restrict__ o) {
  __shared__ __align__(16) bhalf Kb[2][4096];
  __shared__ __align__(16) bhalf Vb[2][4096];
  __shared__ __align__(16) bhalf Pb[4][16][72];
  int tid = threadIdx.x, lane = tid & 63, w = tid >> 6;
  int h = blockIdx.x, kh = h >> 2;
  int qt = 31 - blockIdx.y;
  int qb = qt * 64;
  int m16 = lane & 15, q4 = lane >> 4;
  int wrow0 = qb + w * 16;

  const float C1 = 0.18033688011112042f;  // 0.125 * log2(e)
  const float C2 = 11.541560327111707f;   // 8 * log2(e)

  const bhalf* qp = q + (size_t)(wrow0 + m16) * 2048 + h * 64;
  bhalf8 qf0 = *(const bhalf8*)(qp + q4 * 8);
  bhalf8 qf1 = *(const bhalf8*)(qp + 32 + q4 * 8);

  int srow = tid >> 3;
  int scol = ((tid & 7) ^ (srow & 7)) * 8;
  const bhalf* ksrc = k + (size_t)srow * 512 + kh * 64 + scol;
  const bhalf* vsrc = vt + (size_t)(kh * 64 + srow) * 2048 + scol;
  bhalf* kdst = &Kb[0][0] + w * 512;
  bhalf* vdst = &Vb[0][0] + w * 512;

  auto stage = [&](int c) {
    int buf = c & 1, s0 = c * 64;
#pragma unroll
    for (int j = 0; j < 2; ++j) {
      __builtin_amdgcn_global_load_lds((gas_p)(ksrc + (size_t)(s0 + j * 32) * 512),
                                       (las_p)(kdst + buf * 4096 + j * 2048), 16, 0, 0);
      __builtin_amdgcn_global_load_lds((gas_p)(vsrc + (size_t)(j * 32) * 2048 + s0),
                                       (las_p)(vdst + buf * 4096 + j * 2048), 16, 0, 0);
    }
  };

  f32x4 zero4 = {0.f, 0.f, 0.f, 0.f};
  f32x4 oac[4];
  float psum[4] = {0.f, 0.f, 0.f, 0.f};
#pragma unroll
  for (int ni = 0; ni < 4; ++ni) oac[ni] = zero4;
  int swz = m16 & 7;

  stage(0);
  for (int c = 0; c <= qt; ++c) {
    __syncthreads();
    if (c < qt) stage(c + 1);
    int buf = c & 1, s0 = c * 64;
    if (c < qt) {
      bhalf8 kf[4][2];
#pragma unroll
      for (int st = 0; st < 4; ++st)
#pragma unroll
        for (int ks = 0; ks < 2; ++ks)
          kf[st][ks] = *(const bhalf8*)&Kb[buf][(st * 16 + m16) * 64 + (((ks * 4 + q4) ^ swz) * 8)];
      f32x4 sv[4];
#pragma unroll
      for (int st = 0; st < 4; ++st) {
        f32x4 t0 = __builtin_amdgcn_mfma_f32_16x16x32_bf16(qf0, kf[st][0], zero4, 0, 0, 0);
        sv[st] = __builtin_amdgcn_mfma_f32_16x16x32_bf16(qf1, kf[st][1], t0, 0, 0, 0);
      }
#pragma unroll
      for (int st = 0; st < 4; ++st)
#pragma unroll
        for (int r = 0; r < 4; ++r) {
          float pe = exp2f(sv[st][r] * C1 - C2);
          psum[r] += pe;
          Pb[w][q4 * 4 + r][st * 16 + m16] = (bhalf)pe;
        }
      bhalf8 vf[4][2];
#pragma unroll
      for (int ni = 0; ni < 4; ++ni)
#pragma unroll
        for (int ks = 0; ks < 2; ++ks)
          vf[ni][ks] = *(const bhalf8*)&Vb[buf][(ni * 16 + m16) * 64 + (((ks * 4 + q4) ^ swz) * 8)];
      bhalf8 ap0 = *(const bhalf8*)&Pb[w][m16][q4 * 8];
      bhalf8 ap1 = *(const bhalf8*)&Pb[w][m16][32 + q4 * 8];
#pragma unroll
      for (int ni = 0; ni < 4; ++ni) {
        oac[ni] = __builtin_amdgcn_mfma_f32_16x16x32_bf16(ap0, vf[ni][0], oac[ni], 0, 0, 0);
        oac[ni] = __builtin_amdgcn_mfma_f32_16x16x32_bf16(ap1, vf[ni][1], oac[ni], 0, 0, 0);
      }
    } else {
      bhalf8 kf[4][2];
      f32x4 sv[4];
#pragma unroll
      for (int st = 0; st < 4; ++st)
        if (st <= w) {
#pragma unroll
          for (int ks = 0; ks < 2; ++ks)
            kf[st][ks] = *(const bhalf8*)&Kb[buf][(st * 16 + m16) * 64 + (((ks * 4 + q4) ^ swz) * 8)];
          f32x4 t0 = __builtin_amdgcn_mfma_f32_16x16x32_bf16(qf0, kf[st][0], zero4, 0, 0, 0);
          sv[st] = __builtin_amdgcn_mfma_f32_16x16x32_bf16(qf1, kf[st][1], t0, 0, 0, 0);
        }
      int stwr = (w >= 2) ? 3 : 1;
#pragma unroll
      for (int st = 0; st < 4; ++st) {
        if (st > stwr) continue;
#pragma unroll
        for (int r = 0; r < 4; ++r) {
          float pe = 0.f;
          if (st <= w) {
            int trow = wrow0 + q4 * 4 + r;
            int col = s0 + st * 16 + m16;
            pe = (col <= trow) ? exp2f(sv[st][r] * C1 - C2) : 0.f;
          }
          psum[r] += pe;
          Pb[w][q4 * 4 + r][st * 16 + m16] = (bhalf)pe;
        }
      }
      int ksmax = (w >= 2) ? 1 : 0;
      bhalf8 vf[4][2];
#pragma unroll
      for (int ni = 0; ni < 4; ++ni)
#pragma unroll
        for (int ks = 0; ks < 2; ++ks)
          if (ks <= ksmax)
            vf[ni][ks] = *(const bhalf8*)&Vb[buf][(ni * 16 + m16) * 64 + (((ks * 4 + q4) ^ swz) * 8)];
      bhalf8 ap0 = *(const bhalf8*)&Pb[w][m16][q4 * 8];
#pragma unroll
      for (int ni = 0; ni < 4; ++ni)
        oac[ni] = __builtin_amdgcn_mfma_f32_16x16x32_bf16(ap0, vf[ni][0], oac[ni], 0, 0, 0);
      if (ksmax) {
        bhalf8 ap1 = *(const bhalf8*)&Pb[w][m16][32 + q4 * 8];
#pragma unroll
        for (int ni = 0; ni < 4; ++ni)
          oac[ni] = __builtin_amdgcn_mfma_f32_16x16x32_bf16(ap1, vf[ni][1], oac[ni], 0, 0, 0);
      }
    }
  }
#pragma unroll
  for (int r = 0; r < 4; ++r) {
    float ps = psum[r];
    ps += __shfl_xor(ps, 1);
    ps += __shfl_xor(ps, 2);
    ps += __shfl_xor(ps, 4);
    ps += __shfl_xor(ps, 8);
    psum[r] = 1.0f / ps;
  }
#pragma unroll
  for (int ni = 0; ni < 4; ++ni)
#pragma unroll
    for (int r = 0; r < 4; ++r) {
      int trow = wrow0 + q4 * 4 + r;
      o[(size_t)trow * 2048 + h * 64 + ni * 16 + m16] = (bhalf)(oac[ni][r] * psum[r]);
    }
}

extern "C" void kernel_launch(void* const* d_in, const int* in_sizes, int n_in,
                              void* d_out, int out_size, void* d_ws, size_t ws_size,
                              hipStream_t stream) {
  const int* positions = (const int*)d_in[0];
  const float* hidden  = (const float*)d_in[1];
  const float* w_qkv   = (const float*)d_in[2];
  const float* w_out   = (const float*)d_in[3];
  const float* q_ln    = (const float*)d_in[4];
  const float* k_ln    = (const float*)d_in[5];
  float* out = (float*)d_out;

  char* wsp = (char*)d_ws;
  bhalf* woutT   = (bhalf*)(wsp);                 //  0 .. 8.39 MB
  bhalf* attn_bf = (bhalf*)(wsp + 8388608);       //  8.39 .. 16.78
  float* part0   = (float*)(wsp + 16777216);      // 16.78 .. 33.55 (overlays hid/wqkvT)
  float* part1   = (float*)(wsp + 33554432);      // 33.55 .. 50.33
  bhalf* hid_bf  = (bhalf*)(wsp + 16777216);      // dead after gemm1
  bhalf* wqkvT   = (bhalf*)(wsp + 25165824);      // dead after gemm1
  bhalf* q_bf    = (bhalf*)(wsp + 50331648);      // 50.33 .. 58.72
  bhalf* k_bf    = (bhalf*)(wsp + 58720256);      // 58.72 .. 60.82
  bhalf* vt_g    = (bhalf*)(wsp + 60817408);      // 60.82 .. 62.91
  bhalf* v_bf    = (bhalf*)(wsp + 62914560);      // 62.91 .. 65.01

  cast_bf16_k<<<T_SEQ * HIDN / 1024, 256, 0, stream>>>(hidden, hid_bf, T_SEQ * HIDN);
  transpose_cast64_k<<<dim3(NQKV / 64, HIDN / 64), 256, 0, stream>>>(w_qkv, wqkvT, HIDN, NQKV);
  transpose_cast64_k<<<dim3(HIDN / 64, HIDN / 64), 256, 0, stream>>>(w_out, woutT, HIDN, HIDN);
  gemm1_fused_k<<<dim3(NQKV / 64, T_SEQ / 128), 256, 0, stream>>>(
      hid_bf, wqkvT, positions, q_ln, k_ln, q_bf, k_bf, v_bf);
  transpose_bf16_k<<<dim3(512 / 32, T_SEQ / 32), 256, 0, stream>>>(v_bf, vt_g, T_SEQ, 512);
  attn_k<<<dim3(NQH, 32), 256, 0, stream>>>(q_bf, k_bf, vt_g, attn_bf);
  gemm2_k<<<dim3(HIDN / 64, T_SEQ / 128, 2), 256, 0, stream>>>(attn_bf, woutT, part0);
  add2_k<<<T_SEQ * HIDN / 1024, 256, 0, stream>>>(part0, part1, out);
}